// Round 6
// baseline (63.273 us; speedup 1.0000x reference)
//
#include <hip/hip_runtime.h>
#include <hip/hip_bf16.h>
#include <math.h>

// Chamfer 2D, B=8, N=4096, fp32 — single fused worker kernel.
// Phase 1 (512 blocks): per (dir,n,itile,c) j-chunk mins -> partial[] (4 MB).
//   Inner loop = R2-exact: LDS float4 {-2y0,-2y1,|y|^2}, 3 VALU/pair.
// Last-arrival chaining (no spins, no co-residency assumption):
//   32nd block of group g=(dir,n) runs phase 2: min over c, +|q|^2, sqrt,
//   block-sum -> bs[g]; 2nd arriver on cnt2[n] writes out[n].
// init kernel zeroes the 24 counter words each launch (ws is poisoned).

#define B 8
#define N 4096
#define NJ 16
#define NI 2
#define S1B 256
#define TX 8          // S1B*TX*NI = 4096 queries
#define JC (N / NJ)   // 256 db points per phase-1 block

// ws layout: partial[NJ*2*B*N] | bs[16] | cnt1[16] | cnt2[8]

__global__ __launch_bounds__(64) void chamfer_init(unsigned* __restrict__ cnt) {
  if (threadIdx.x < 24) cnt[threadIdx.x] = 0u;
}

__global__ __launch_bounds__(S1B) void chamfer_mega(
    const float2* __restrict__ P1, const float2* __restrict__ P2,
    float* __restrict__ partial, float* __restrict__ bs,
    unsigned* __restrict__ cnt1, unsigned* __restrict__ cnt2,
    float* __restrict__ out) {
  __shared__ float4 yb[JC];
  __shared__ float red[S1B];
  __shared__ int flag;

  int b = blockIdx.x;
  int c = b & (NJ - 1);
  int itile = (b >> 4) & (NI - 1);
  int n = (b >> 5) & (B - 1);
  int dir = b >> 8;
  int g = dir * B + n;

  const float2* __restrict__ Q = dir ? P2 : P1;  // queries
  const float2* __restrict__ D = dir ? P1 : P2;  // database

  // ---------- phase 1 ----------
  const float2* dbase = D + n * N + c * JC;
  for (int t = threadIdx.x; t < JC; t += S1B) {
    float2 p = dbase[t];
    yb[t] = make_float4(-2.f * p.x, -2.f * p.y,
                        fmaf(p.x, p.x, p.y * p.y), 0.f);
  }
  __syncthreads();

  float qx[TX], qy[TX], m[TX];
  const float2* qbase = Q + n * N + itile * (S1B * TX) + threadIdx.x;
#pragma unroll
  for (int k = 0; k < TX; ++k) {
    float2 q = qbase[k * S1B];
    qx[k] = q.x; qy[k] = q.y;
    m[k] = INFINITY;
  }

#pragma unroll 4
  for (int j = 0; j < JC; ++j) {
    float4 y = yb[j];
#pragma unroll
    for (int k = 0; k < TX; ++k) {
      float t = fmaf(qx[k], y.x, fmaf(qy[k], y.y, y.z));
      m[k] = fminf(m[k], t);
    }
  }

  float* __restrict__ dst = partial + (((size_t)c * 2 + dir) * B + n) * N
                          + itile * (S1B * TX) + threadIdx.x;
#pragma unroll
  for (int k = 0; k < TX; ++k) dst[k * S1B] = m[k];

  // publish + elect the phase-2 executor (last arrival in group g)
  __syncthreads();                       // drains this block's stores (vmcnt 0)
  if (threadIdx.x == 0) {
    __threadfence();                     // release to device scope
    unsigned old = atomicAdd(&cnt1[g], 1u);
    flag = (old == NI * NJ - 1) ? 1 : 0;
  }
  __syncthreads();
  if (!flag) return;

  __threadfence();                       // acquire (all threads)

  // ---------- phase 2: one block per group ----------
  float acc = 0.f;
  const float* pg = partial + ((size_t)dir * B + n) * N;  // c-stride = 2*B*N
  for (int s = 0; s < N / S1B; ++s) {
    int i = threadIdx.x + s * S1B;
    float mm = INFINITY;
#pragma unroll
    for (int cc = 0; cc < NJ; ++cc) {
      float v = __hip_atomic_load(pg + (size_t)cc * 2 * B * N + i,
                                  __ATOMIC_RELAXED, __HIP_MEMORY_SCOPE_AGENT);
      mm = fminf(mm, v);
    }
    float2 q = Q[n * N + i];
    acc += sqrtf(fmaxf(mm + fmaf(q.x, q.x, q.y * q.y), 0.f));
  }
  red[threadIdx.x] = acc;
  __syncthreads();
  for (int s = S1B / 2; s > 0; s >>= 1) {
    if (threadIdx.x < s) red[threadIdx.x] += red[threadIdx.x + s];
    __syncthreads();
  }

  // ---------- phase 3: 2nd arriver per n writes out[n] ----------
  if (threadIdx.x == 0) {
    bs[g] = red[0];
    __threadfence();                     // release bs[g]
    unsigned old2 = atomicAdd(&cnt2[n], 1u);
    if (old2 == 1) {
      __threadfence();                   // acquire
      float v0 = __hip_atomic_load(&bs[0 * B + n],
                                   __ATOMIC_RELAXED, __HIP_MEMORY_SCOPE_AGENT);
      float v1 = __hip_atomic_load(&bs[1 * B + n],
                                   __ATOMIC_RELAXED, __HIP_MEMORY_SCOPE_AGENT);
      out[n] = (v0 + v1) * (0.5f / (float)N);
    }
  }
}

extern "C" void kernel_launch(void* const* d_in, const int* in_sizes, int n_in,
                              void* d_out, int out_size, void* d_ws, size_t ws_size,
                              hipStream_t stream) {
  const float2* P1 = (const float2*)d_in[0];
  const float2* P2 = (const float2*)d_in[1];
  float* out = (float*)d_out;

  float* partial = (float*)d_ws;
  float* bs = partial + (size_t)NJ * 2 * B * N;
  unsigned* cnt = (unsigned*)(bs + 16);   // cnt1[16] then cnt2[8]

  chamfer_init<<<dim3(1), 64, 0, stream>>>(cnt);
  chamfer_mega<<<dim3(2 * B * NI * NJ), S1B, 0, stream>>>(
      P1, P2, partial, bs, cnt, cnt + 16, out);
}

// Round 7
// 30.226 us; speedup vs baseline: 2.0933x; 2.0933x over previous
//
#include <hip/hip_runtime.h>
#include <hip/hip_bf16.h>
#include <math.h>

// Chamfer 2D, B=8, N=4096, fp32 — atomicMin formulation, no partial matrix.
// mind2[dir][n][i] (uint bits of d^2 >= 0): float order == uint order, so
// atomicMin is an exact, order-independent min => deterministic output.
// Stage1 = R2's proven inner loop (LDS float4 {-2y0,-2y1,|y|^2}, 3 VALU/pair),
// epilogue folds m[k]+|q|^2 into mind2 via atomicMin (8 atomics/thread).
// Stage2: 8 blocks read 2*4096 d^2 each, sqrt, fixed-tree sum -> out[n].

#define B 8
#define N 4096
#define NJ 16
#define NI 2
#define S1B 256
#define TX 8          // S1B*TX*NI = 4096 queries per (dir,n)
#define JC (N / NJ)   // 256 db points per stage1 block

// ws layout: mind2[2*B*N] uints (256 KB)

__global__ __launch_bounds__(256) void chamfer_init(unsigned* __restrict__ mind2) {
  mind2[blockIdx.x * 256 + threadIdx.x] = 0x7F800000u;  // +inf
}

__global__ __launch_bounds__(S1B) void chamfer_stage1(
    const float2* __restrict__ P1, const float2* __restrict__ P2,
    unsigned* __restrict__ mind2) {
  __shared__ float4 yb[JC];

  int b = blockIdx.x;
  int c = b & (NJ - 1);
  int itile = (b >> 4) & (NI - 1);
  int n = (b >> 5) & (B - 1);
  int dir = b >> 8;

  const float2* __restrict__ Q = dir ? P2 : P1;  // queries
  const float2* __restrict__ D = dir ? P1 : P2;  // database

  const float2* dbase = D + n * N + c * JC;
  for (int t = threadIdx.x; t < JC; t += S1B) {
    float2 p = dbase[t];
    yb[t] = make_float4(-2.f * p.x, -2.f * p.y,
                        fmaf(p.x, p.x, p.y * p.y), 0.f);
  }
  __syncthreads();

  float qx[TX], qy[TX], qq[TX], m[TX];
  const float2* qbase = Q + n * N + itile * (S1B * TX) + threadIdx.x;
#pragma unroll
  for (int k = 0; k < TX; ++k) {
    float2 q = qbase[k * S1B];
    qx[k] = q.x; qy[k] = q.y;
    qq[k] = fmaf(q.x, q.x, q.y * q.y);
    m[k] = INFINITY;
  }

  // wave-uniform LDS broadcast; 3 VALU slots per pair
#pragma unroll 4
  for (int j = 0; j < JC; ++j) {
    float4 y = yb[j];
#pragma unroll
    for (int k = 0; k < TX; ++k) {
      float t = fmaf(qx[k], y.x, fmaf(qy[k], y.y, y.z));
      m[k] = fminf(m[k], t);
    }
  }

  unsigned* __restrict__ dst =
      mind2 + (dir * B + n) * N + itile * (S1B * TX) + threadIdx.x;
#pragma unroll
  for (int k = 0; k < TX; ++k) {
    float d2 = fmaxf(m[k] + qq[k], 0.f);   // true squared distance, >= 0
    atomicMin(dst + k * S1B, __float_as_uint(d2));
  }
}

// grid = B blocks; each reduces both dirs for its n.
__global__ __launch_bounds__(256) void chamfer_stage2(
    const unsigned* __restrict__ mind2, float* __restrict__ out) {
  int n = blockIdx.x;
  float acc = 0.f;
#pragma unroll
  for (int dir = 0; dir < 2; ++dir) {
    const unsigned* __restrict__ p = mind2 + (dir * B + n) * N;
#pragma unroll
    for (int s = 0; s < N / 256; ++s)
      acc += sqrtf(__uint_as_float(p[threadIdx.x + s * 256]));
  }
  __shared__ float red[256];
  red[threadIdx.x] = acc;
  __syncthreads();
  for (int s = 128; s > 0; s >>= 1) {
    if (threadIdx.x < s) red[threadIdx.x] += red[threadIdx.x + s];
    __syncthreads();
  }
  if (threadIdx.x == 0) out[n] = red[0] * (0.5f / (float)N);
}

extern "C" void kernel_launch(void* const* d_in, const int* in_sizes, int n_in,
                              void* d_out, int out_size, void* d_ws, size_t ws_size,
                              hipStream_t stream) {
  const float2* P1 = (const float2*)d_in[0];
  const float2* P2 = (const float2*)d_in[1];
  float* out = (float*)d_out;
  unsigned* mind2 = (unsigned*)d_ws;

  chamfer_init<<<dim3(2 * B * N / 256), 256, 0, stream>>>(mind2);
  chamfer_stage1<<<dim3(2 * B * NI * NJ), S1B, 0, stream>>>(P1, P2, mind2);
  chamfer_stage2<<<dim3(B), 256, 0, stream>>>(mind2, out);
}